// Round 1
// baseline (2407.797 us; speedup 1.0000x reference)
//
#include <hip/hip_runtime.h>
#include <math.h>

// Problem constants
#define BB 4
#define SS 2048
#define DD 1024
#define HH 2048
#define AD 128
#define EE 8
#define MM (BB*SS)   // 8192

#define TS 64
#define KT 16

__device__ __forceinline__ float silu_f(float x){ return x / (1.f + expf(-x)); }

// C[M,N] = epi(A[M,K] @ B[N,K]^T), all row-major packed (lda=K, ldb=K, ldc=N).
// z-batched via strides. ACT: 0=none, 1=silu(clip(.,-5,5)).
template<int ACT>
__global__ __launch_bounds__(256) void gemm_nt(
    const float* __restrict__ A, const float* __restrict__ B, float* __restrict__ C,
    int M, int N, int K, long sA, long sB, long sC,
    const float* __restrict__ bias, const float* __restrict__ rowscale,
    float alpha, int accum)
{
    __shared__ __align__(16) float As[KT][TS+4];
    __shared__ __align__(16) float Bs[KT][TS+4];
    A += (long)blockIdx.z * sA;
    B += (long)blockIdx.z * sB;
    C += (long)blockIdx.z * sC;
    const int tx = threadIdx.x, ty = threadIdx.y;
    const int t  = ty * 16 + tx;
    const int m0 = blockIdx.y * TS, n0 = blockIdx.x * TS;
    const int lr = t >> 2;          // 0..63
    const int lc = (t & 3) * 4;     // 0,4,8,12
    float acc[4][4] = {};
    for (int k0 = 0; k0 < K; k0 += KT) {
        #pragma unroll
        for (int i = 0; i < 4; ++i) As[lc+i][lr] = A[(long)(m0+lr)*K + k0 + lc + i];
        #pragma unroll
        for (int i = 0; i < 4; ++i) Bs[lc+i][lr] = B[(long)(n0+lr)*K + k0 + lc + i];
        __syncthreads();
        #pragma unroll
        for (int kk = 0; kk < KT; ++kk) {
            const float4 av = *(const float4*)&As[kk][ty*4];
            const float4 bv = *(const float4*)&Bs[kk][tx*4];
            const float a[4] = {av.x, av.y, av.z, av.w};
            const float b[4] = {bv.x, bv.y, bv.z, bv.w};
            #pragma unroll
            for (int i = 0; i < 4; ++i)
                #pragma unroll
                for (int j = 0; j < 4; ++j)
                    acc[i][j] += a[i]*b[j];
        }
        __syncthreads();
    }
    #pragma unroll
    for (int i = 0; i < 4; ++i) {
        const int m = m0 + ty*4 + i;
        const float rsc = rowscale ? rowscale[m] : 1.f;
        #pragma unroll
        for (int j = 0; j < 4; ++j) {
            const int n = n0 + tx*4 + j;
            float v = acc[i][j];
            if (bias) v += bias[n];
            if (ACT == 1) { v = fminf(fmaxf(v, -5.f), 5.f); v = silu_f(v); }
            v *= alpha * rsc;
            const long idx = (long)m * N + n;
            if (accum) C[idx] += v; else C[idx] = v;
        }
    }
}

// C[M,N] = A[M,K] @ B[K,N], row-major packed (lda=K, ldb=N, ldc=N). Plain store.
__global__ __launch_bounds__(256) void gemm_nn(
    const float* __restrict__ A, const float* __restrict__ B, float* __restrict__ C,
    int M, int N, int K)
{
    __shared__ __align__(16) float As[KT][TS+4];
    __shared__ __align__(16) float Bs[KT][TS+4];
    const int tx = threadIdx.x, ty = threadIdx.y;
    const int t  = ty * 16 + tx;
    const int m0 = blockIdx.y * TS, n0 = blockIdx.x * TS;
    const int lr = t >> 2;
    const int lc = (t & 3) * 4;
    const int bk = t >> 4;          // 0..15 (k row for B load)
    const int bc = (t & 15) * 4;    // 0..60 (n col for B load)
    float acc[4][4] = {};
    for (int k0 = 0; k0 < K; k0 += KT) {
        #pragma unroll
        for (int i = 0; i < 4; ++i) As[lc+i][lr] = A[(long)(m0+lr)*K + k0 + lc + i];
        #pragma unroll
        for (int i = 0; i < 4; ++i) Bs[bk][bc+i] = B[(long)(k0+bk)*N + n0 + bc + i];
        __syncthreads();
        #pragma unroll
        for (int kk = 0; kk < KT; ++kk) {
            const float4 av = *(const float4*)&As[kk][ty*4];
            const float4 bv = *(const float4*)&Bs[kk][tx*4];
            const float a[4] = {av.x, av.y, av.z, av.w};
            const float b[4] = {bv.x, bv.y, bv.z, bv.w};
            #pragma unroll
            for (int i = 0; i < 4; ++i)
                #pragma unroll
                for (int j = 0; j < 4; ++j)
                    acc[i][j] += a[i]*b[j];
        }
        __syncthreads();
    }
    #pragma unroll
    for (int i = 0; i < 4; ++i) {
        const int m = m0 + ty*4 + i;
        #pragma unroll
        for (int j = 0; j < 4; ++j) {
            const int n = n0 + tx*4 + j;
            C[(long)m * N + n] = acc[i][j];
        }
    }
}

// hidden[M,N] = silu(x@Wg^T + bg) * (x@Wu^T + bu)
__global__ __launch_bounds__(256) void gemm_upgate(
    const float* __restrict__ X, const float* __restrict__ Wu, const float* __restrict__ bu,
    const float* __restrict__ Wg, const float* __restrict__ bg,
    float* __restrict__ hidden, int M, int N, int K)
{
    __shared__ __align__(16) float As[KT][TS+4];
    __shared__ __align__(16) float Us[KT][TS+4];
    __shared__ __align__(16) float Gs[KT][TS+4];
    const int tx = threadIdx.x, ty = threadIdx.y;
    const int t  = ty * 16 + tx;
    const int m0 = blockIdx.y * TS, n0 = blockIdx.x * TS;
    const int lr = t >> 2;
    const int lc = (t & 3) * 4;
    float accu[4][4] = {};
    float accg[4][4] = {};
    for (int k0 = 0; k0 < K; k0 += KT) {
        #pragma unroll
        for (int i = 0; i < 4; ++i) As[lc+i][lr] = X [(long)(m0+lr)*K + k0 + lc + i];
        #pragma unroll
        for (int i = 0; i < 4; ++i) Us[lc+i][lr] = Wu[(long)(n0+lr)*K + k0 + lc + i];
        #pragma unroll
        for (int i = 0; i < 4; ++i) Gs[lc+i][lr] = Wg[(long)(n0+lr)*K + k0 + lc + i];
        __syncthreads();
        #pragma unroll
        for (int kk = 0; kk < KT; ++kk) {
            const float4 av = *(const float4*)&As[kk][ty*4];
            const float4 uv = *(const float4*)&Us[kk][tx*4];
            const float4 gv = *(const float4*)&Gs[kk][tx*4];
            const float a[4] = {av.x, av.y, av.z, av.w};
            const float u[4] = {uv.x, uv.y, uv.z, uv.w};
            const float g[4] = {gv.x, gv.y, gv.z, gv.w};
            #pragma unroll
            for (int i = 0; i < 4; ++i)
                #pragma unroll
                for (int j = 0; j < 4; ++j) {
                    accu[i][j] += a[i]*u[j];
                    accg[i][j] += a[i]*g[j];
                }
        }
        __syncthreads();
    }
    #pragma unroll
    for (int i = 0; i < 4; ++i) {
        const int m = m0 + ty*4 + i;
        #pragma unroll
        for (int j = 0; j < 4; ++j) {
            const int n = n0 + tx*4 + j;
            const float u = accu[i][j] + bu[n];
            float g = accg[i][j] + bg[n];
            hidden[(long)m * N + n] = silu_f(g) * u;
        }
    }
}

// Row LayerNorm over last dim = 128. One row per block, 128 threads.
__global__ __launch_bounds__(128) void ln_rows(
    const float* __restrict__ in, float* __restrict__ out,
    const float* __restrict__ g, const float* __restrict__ b)
{
    const int r = blockIdx.x, tid = threadIdx.x;
    const float v = in[(long)r * AD + tid];
    __shared__ float red[AD], red2[AD];
    red[tid] = v; red2[tid] = v*v;
    __syncthreads();
    for (int s = 64; s > 0; s >>= 1) {
        if (tid < s) { red[tid] += red[tid+s]; red2[tid] += red2[tid+s]; }
        __syncthreads();
    }
    const float mean = red[0] * (1.f/AD);
    const float var  = red2[0] * (1.f/AD) - mean*mean;
    const float rs   = rsqrtf(var + 1e-5f);
    out[(long)r * AD + tid] = (v - mean) * rs * g[tid] + b[tid];
}

// hw[m,:] = sum_e wmask[m,e] * LN(h[e,m,:]; eg[e], eb[e]);  sumw[m] = sum_e w[m,e]
__global__ __launch_bounds__(128) void expert_combine(
    const float* __restrict__ h, const float* __restrict__ ew,
    const float* __restrict__ eg, const float* __restrict__ eb,
    float* __restrict__ hw, float* __restrict__ sumw)
{
    const int m = blockIdx.x, tid = threadIdx.x;
    __shared__ float red[AD], red2[AD];
    __shared__ float wsh[EE];
    if (tid < EE) wsh[tid] = ew[(long)m * EE + tid];
    __syncthreads();
    float acc = 0.f;
    for (int e = 0; e < EE; ++e) {
        const float v = h[((long)e * MM + m) * AD + tid];
        red[tid] = v; red2[tid] = v*v;
        __syncthreads();
        for (int s = 64; s > 0; s >>= 1) {
            if (tid < s) { red[tid] += red[tid+s]; red2[tid] += red2[tid+s]; }
            __syncthreads();
        }
        const float mean = red[0] * (1.f/AD);
        const float var  = red2[0] * (1.f/AD) - mean*mean;
        const float rs   = rsqrtf(var + 1e-5f);
        const float nv   = (v - mean) * rs * eg[e*AD + tid] + eb[e*AD + tid];
        const float w    = wsh[e];
        acc += (w > 0.f ? w : 0.f) * nv;
        __syncthreads();   // protect red[] before next expert overwrites
    }
    hw[(long)m * AD + tid] = acc;
    if (tid == 0) {
        float s = 0.f;
        for (int e = 0; e < EE; ++e) s += wsh[e];
        sumw[m] = s;
    }
}

extern "C" void kernel_launch(void* const* d_in, const int* in_sizes, int n_in,
                              void* d_out, int out_size, void* d_ws, size_t ws_size,
                              hipStream_t stream) {
    const float* x    = (const float*)d_in[0];
    const float* ew   = (const float*)d_in[1];
    const float* Wu   = (const float*)d_in[2];
    const float* bu   = (const float*)d_in[3];
    const float* Wg   = (const float*)d_in[4];
    const float* bg   = (const float*)d_in[5];
    const float* Wd   = (const float*)d_in[6];
    const float* bd   = (const float*)d_in[7];
    const float* Wpre = (const float*)d_in[8];
    const float* bpre = (const float*)d_in[9];
    const float* Wpost= (const float*)d_in[10];
    const float* bpost= (const float*)d_in[11];
    const float* ln_g = (const float*)d_in[12];
    const float* ln_b = (const float*)d_in[13];
    const float* Wap  = (const float*)d_in[14];
    const float* Aex  = (const float*)d_in[15];
    const float* eg   = (const float*)d_in[16];
    const float* eb   = (const float*)d_in[17];
    const float* Wp   = (const float*)d_in[18];
    const float* Wo   = (const float*)d_in[19];
    float* out = (float*)d_out;

    // Workspace layout (floats). h_buf aliases hidden (h dead before hidden written).
    float* w = (float*)d_ws;
    float* pre      = w; w += (long)MM * AD;        // 1,048,576
    float* adapt_in = w; w += (long)MM * AD;
    float* sumw     = w; w += MM;
    float* Wc       = w; w += (long)DD * AD;        // 131,072
    float* hw       = w; w += (long)MM * AD;
    float* ao       = w; w += (long)MM * AD;
    float* adaptb   = w; w += (long)MM * AD;
    float* awbuf    = w; w += (long)SS * SS;        // 4,194,304 (one batch of scores)
    float* hidden   = w;                            // 16,777,216
    float* hbuf     = hidden;                       // 8*MM*AD = 8,388,608 <= hidden

    const dim3 blk(16, 16, 1);

    // 1. pre = x @ Wpre^T + bpre           [8192,128]
    gemm_nt<0><<<dim3(AD/TS, MM/TS, 1), blk, 0, stream>>>(
        x, Wpre, pre, MM, AD, DD, 0, 0, 0, bpre, nullptr, 1.f, 0);
    // 2. adapt_in = LN(pre)
    ln_rows<<<dim3(MM), dim3(AD), 0, stream>>>(pre, adapt_in, ln_g, ln_b);
    // 3. h[e] = pre @ A[e]^T               [8,8192,128]
    gemm_nt<0><<<dim3(AD/TS, MM/TS, EE), blk, 0, stream>>>(
        pre, Aex, hbuf, MM, AD, AD, 0, (long)AD*AD, (long)MM*AD, nullptr, nullptr, 1.f, 0);
    // 4. hw = sum_e wmask*LN(h[e]); sumw
    expert_combine<<<dim3(MM), dim3(AD), 0, stream>>>(hbuf, ew, eg, eb, hw, sumw);
    // 5. Wc = Wo @ Wp                      [1024,128]
    gemm_nn<<<dim3(AD/TS, DD/TS, 1), blk, 0, stream>>>(Wo, Wp, Wc, DD, AD, HH);
    // 6. out = 0.1 * hw @ Wc^T             [8192,1024]
    gemm_nt<0><<<dim3(DD/TS, MM/TS, 1), blk, 0, stream>>>(
        hw, Wc, out, MM, DD, AD, 0, 0, 0, nullptr, nullptr, 0.1f, 0);
    // 7. hidden = silu(x@Wg^T+bg)*(x@Wu^T+bu)   [8192,2048]
    gemm_upgate<<<dim3(HH/TS, MM/TS, 1), blk, 0, stream>>>(
        x, Wu, bu, Wg, bg, hidden, MM, HH, DD);
    // 8. ao = hidden @ Wpost^T + bpost     [8192,128]
    gemm_nt<0><<<dim3(AD/TS, MM/TS, 1), blk, 0, stream>>>(
        hidden, Wpost, ao, MM, AD, HH, 0, 0, 0, bpost, nullptr, 1.f, 0);
    // 9. ao = LN(ao) in-place
    ln_rows<<<dim3(MM), dim3(AD), 0, stream>>>(ao, ao, ln_g, ln_b);
    // 10. per-batch attention-like block
    for (int b = 0; b < BB; ++b) {
        const float* ai_b = adapt_in + (long)b * SS * AD;
        const float* ao_b = ao       + (long)b * SS * AD;
        float*       ad_b = adaptb   + (long)b * SS * AD;
        // aw = silu(clip(ai_b @ ao_b^T))   [2048,2048]
        gemm_nt<1><<<dim3(SS/TS, SS/TS, 1), blk, 0, stream>>>(
            ai_b, ao_b, awbuf, SS, SS, AD, 0, 0, 0, nullptr, nullptr, 1.f, 0);
        // adapt_b = aw @ ai_b              [2048,128]
        gemm_nn<<<dim3(AD/TS, SS/TS, 1), blk, 0, stream>>>(awbuf, ai_b, ad_b, SS, AD, SS);
    }
    // 11. hidden += 0.1 * adapt @ Wap^T    [8192,2048]
    gemm_nt<0><<<dim3(HH/TS, MM/TS, 1), blk, 0, stream>>>(
        adaptb, Wap, hidden, MM, HH, AD, 0, 0, 0, nullptr, nullptr, 0.1f, 1);
    // 12. out += sumw[m] * (hidden @ Wd^T + bd)
    gemm_nt<0><<<dim3(DD/TS, MM/TS, 1), blk, 0, stream>>>(
        hidden, Wd, out, MM, DD, HH, 0, 0, 0, bd, sumw, 1.f, 1);
}

// Round 2
// 566.018 us; speedup vs baseline: 4.2539x; 4.2539x over previous
//
#include <hip/hip_runtime.h>
#include <math.h>

// Problem constants
#define BB 4
#define SS 2048
#define DD 1024
#define HH 2048
#define AD 128
#define EE 8
#define MM (BB*SS)   // 8192

typedef unsigned short u16;
typedef short bf16x8 __attribute__((ext_vector_type(8)));
typedef float f32x4 __attribute__((ext_vector_type(4)));

__device__ __forceinline__ float silu_f(float x){ return x / (1.f + __expf(-x)); }

__device__ __forceinline__ u16 f2bf(float f){
    union { float f; unsigned u; } c; c.f = f;
    unsigned r = (c.u + 0x7FFFu + ((c.u >> 16) & 1u)) >> 16;
    return (u16)r;
}
__device__ __forceinline__ float bf2f(u16 u){
    union { unsigned u; float f; } c; c.u = ((unsigned)u) << 16;
    return c.f;
}

// async global->LDS, 16B per lane. LDS dest must be wave-uniform base + lane*16.
__device__ __forceinline__ void gld16(const u16* g, u16* l){
    __builtin_amdgcn_global_load_lds((const __attribute__((address_space(1))) void*)g,
                                     (__attribute__((address_space(3))) void*)l, 16, 0, 0);
}

// ---------------------------------------------------------------------------
// NT bf16 MFMA GEMM: C[M,N] = epi(A[M,K] @ B[N,K]^T). A,B bf16 row-major
// (K contiguous). 128x128 tile, BK=32, 4 waves each computing 64x64.
// EPI: 0 f32 store alpha*(acc+bias)
//      1 bf16 store f2bf(alpha*(acc+bias))
//      2 bf16 store silu(clip(acc,-5,5))
//      3 bf16 store f2bf(bf2f(Haux[idx]) + alpha*acc)   (in-place ok)
//      4 f32 C[idx] += rowscale[row]*(acc+bias[col])
// ---------------------------------------------------------------------------
template<int EPI>
__global__ __launch_bounds__(256,2) void mfma_nt(
    const u16* __restrict__ A, const u16* __restrict__ B, void* Cv,
    int M, int N, int K, long sA, long sB, long sC,
    const float* __restrict__ bias, const float* __restrict__ rowscale,
    u16* Haux, float alpha)
{
    __shared__ __align__(16) u16 As[128*32];
    __shared__ __align__(16) u16 Bs[128*32];
    const int t = threadIdx.x;
    const int lane = t & 63;
    const int wv = t >> 6;
    const int m0 = blockIdx.y * 128, n0 = blockIdx.x * 128;
    const u16* Ab = A + (long)blockIdx.z * sA;
    const u16* Bb = B + (long)blockIdx.z * sB;
    const int srow = t >> 2, scol = (t & 3) * 8;
    const u16* ga0 = Ab + (long)(m0 + srow) * K + scol;
    const u16* ga1 = ga0 + 64L * K;
    const u16* gb0 = Bb + (long)(n0 + srow) * K + scol;
    const u16* gb1 = gb0 + 64L * K;
    u16* la0 = As + t * 8;  u16* la1 = As + 2048 + t * 8;
    u16* lb0 = Bs + t * 8;  u16* lb1 = Bs + 2048 + t * 8;
    const int fr = lane & 15, q = lane >> 4;
    const int wm = (wv & 1) * 64, wn = (wv >> 1) * 64;

    f32x4 acc[4][4] = {};
    for (int k0 = 0; k0 < K; k0 += 32) {
        gld16(ga0 + k0, la0);
        gld16(ga1 + k0, la1);
        gld16(gb0 + k0, lb0);
        gld16(gb1 + k0, lb1);
        __syncthreads();   // drains vmcnt before barrier
        bf16x8 af[4], bfr[4];
        #pragma unroll
        for (int i = 0; i < 4; ++i) af[i]  = *(const bf16x8*)&As[(wm + i*16 + fr)*32 + q*8];
        #pragma unroll
        for (int i = 0; i < 4; ++i) bfr[i] = *(const bf16x8*)&Bs[(wn + i*16 + fr)*32 + q*8];
        #pragma unroll
        for (int mi = 0; mi < 4; ++mi)
            #pragma unroll
            for (int ni = 0; ni < 4; ++ni)
                acc[mi][ni] = __builtin_amdgcn_mfma_f32_16x16x32_bf16(af[mi], bfr[ni], acc[mi][ni], 0, 0, 0);
        __syncthreads();
    }

    float* Cf = (float*)Cv + (long)blockIdx.z * sC;
    u16*   Cb = (u16*)Cv   + (long)blockIdx.z * sC;
    u16*   Hb = Haux ? Haux + (long)blockIdx.z * sC : (u16*)0;
    #pragma unroll
    for (int mi = 0; mi < 4; ++mi) {
        #pragma unroll
        for (int ni = 0; ni < 4; ++ni) {
            const int col = n0 + wn + ni*16 + fr;
            #pragma unroll
            for (int r = 0; r < 4; ++r) {
                const int row = m0 + wm + mi*16 + q*4 + r;
                const long idx = (long)row * N + col;
                float v = acc[mi][ni][r];
                if (EPI == 0) {
                    if (bias) v += bias[col];
                    Cf[idx] = alpha * v;
                } else if (EPI == 1) {
                    if (bias) v += bias[col];
                    Cb[idx] = f2bf(alpha * v);
                } else if (EPI == 2) {
                    v = fminf(fmaxf(v, -5.f), 5.f);
                    Cb[idx] = f2bf(silu_f(v));
                } else if (EPI == 3) {
                    Cb[idx] = f2bf(bf2f(Hb[idx]) + alpha * v);
                } else {
                    v = (v + bias[col]) * rowscale[row];
                    Cf[idx] += v;
                }
            }
        }
    }
}

// ---------------------------------------------------------------------------
// Fused up/gate: H[M,HH] = bf16( silu(X@Wg^T+bg) * (X@Wu^T+bu) )
// Tile 128(M) x 64(N), dual B, BK=32. 4 waves as 2x2, each 64x32 per output.
// ---------------------------------------------------------------------------
__global__ __launch_bounds__(256,2) void mfma_upgate(
    const u16* __restrict__ X, const u16* __restrict__ Wu_, const u16* __restrict__ Wg_,
    const float* __restrict__ bu, const float* __restrict__ bg, u16* __restrict__ H)
{
    __shared__ __align__(16) u16 Xs[128*32];
    __shared__ __align__(16) u16 Us[64*32];
    __shared__ __align__(16) u16 Gs[64*32];
    const int t = threadIdx.x, lane = t & 63, wv = t >> 6;
    const int m0 = blockIdx.y * 128, n0 = blockIdx.x * 64;
    const int srow = t >> 2, scol = (t & 3) * 8;
    const u16* gx0 = X   + (long)(m0 + srow) * DD + scol;
    const u16* gx1 = gx0 + 64L * DD;
    const u16* gu  = Wu_ + (long)(n0 + srow) * DD + scol;
    const u16* gg  = Wg_ + (long)(n0 + srow) * DD + scol;
    const int fr = lane & 15, q = lane >> 4;
    const int wm = (wv & 1) * 64, wn = (wv >> 1) * 32;

    f32x4 accu[4][2] = {};
    f32x4 accg[4][2] = {};
    for (int k0 = 0; k0 < DD; k0 += 32) {
        gld16(gx0 + k0, Xs + t*8);
        gld16(gx1 + k0, Xs + 2048 + t*8);
        gld16(gu  + k0, Us + t*8);
        gld16(gg  + k0, Gs + t*8);
        __syncthreads();
        bf16x8 xf[4], uf[2], gf[2];
        #pragma unroll
        for (int i = 0; i < 4; ++i) xf[i] = *(const bf16x8*)&Xs[(wm + i*16 + fr)*32 + q*8];
        #pragma unroll
        for (int i = 0; i < 2; ++i) {
            uf[i] = *(const bf16x8*)&Us[(wn + i*16 + fr)*32 + q*8];
            gf[i] = *(const bf16x8*)&Gs[(wn + i*16 + fr)*32 + q*8];
        }
        #pragma unroll
        for (int mi = 0; mi < 4; ++mi)
            #pragma unroll
            for (int ni = 0; ni < 2; ++ni) {
                accu[mi][ni] = __builtin_amdgcn_mfma_f32_16x16x32_bf16(xf[mi], uf[ni], accu[mi][ni], 0, 0, 0);
                accg[mi][ni] = __builtin_amdgcn_mfma_f32_16x16x32_bf16(xf[mi], gf[ni], accg[mi][ni], 0, 0, 0);
            }
        __syncthreads();
    }
    #pragma unroll
    for (int mi = 0; mi < 4; ++mi) {
        #pragma unroll
        for (int ni = 0; ni < 2; ++ni) {
            const int col = n0 + wn + ni*16 + fr;
            #pragma unroll
            for (int r = 0; r < 4; ++r) {
                const int row = m0 + wm + mi*16 + q*4 + r;
                const float u = accu[mi][ni][r] + bu[col];
                const float g = accg[mi][ni][r] + bg[col];
                H[(long)row * HH + col] = f2bf(silu_f(g) * u);
            }
        }
    }
}

// LayerNorm over last dim 128 -> bf16 out. Input f32 or bf16.
template<typename T>
__global__ __launch_bounds__(128) void ln_rows_bf(
    const T* __restrict__ in, u16* __restrict__ out,
    const float* __restrict__ g, const float* __restrict__ b)
{
    const int r = blockIdx.x, tid = threadIdx.x;
    float v;
    if (sizeof(T) == 2) v = bf2f(((const u16*)in)[(long)r * AD + tid]);
    else                v = ((const float*)in)[(long)r * AD + tid];
    __shared__ float red[AD], red2[AD];
    red[tid] = v; red2[tid] = v*v;
    __syncthreads();
    for (int s = 64; s > 0; s >>= 1) {
        if (tid < s) { red[tid] += red[tid+s]; red2[tid] += red2[tid+s]; }
        __syncthreads();
    }
    const float mean = red[0] * (1.f/AD);
    const float var  = red2[0] * (1.f/AD) - mean*mean;
    const float rs   = rsqrtf(var + 1e-5f);
    out[(long)r * AD + tid] = f2bf((v - mean) * rs * g[tid] + b[tid]);
}

// hw[m,:] = bf16( sum_e max(ew,0)*LN(h[e,m,:]) );  sumw[m] = sum_e ew[m,e]
__global__ __launch_bounds__(128) void expert_combine(
    const float* __restrict__ h, const float* __restrict__ ew,
    const float* __restrict__ eg, const float* __restrict__ eb,
    u16* __restrict__ hw, float* __restrict__ sumw)
{
    const int m = blockIdx.x, tid = threadIdx.x;
    __shared__ float red[AD], red2[AD];
    __shared__ float wsh[EE];
    if (tid < EE) wsh[tid] = ew[(long)m * EE + tid];
    __syncthreads();
    float acc = 0.f;
    for (int e = 0; e < EE; ++e) {
        const float v = h[((long)e * MM + m) * AD + tid];
        red[tid] = v; red2[tid] = v*v;
        __syncthreads();
        for (int s = 64; s > 0; s >>= 1) {
            if (tid < s) { red[tid] += red[tid+s]; red2[tid] += red2[tid+s]; }
            __syncthreads();
        }
        const float mean = red[0] * (1.f/AD);
        const float var  = red2[0] * (1.f/AD) - mean*mean;
        const float rs   = rsqrtf(var + 1e-5f);
        const float nv   = (v - mean) * rs * eg[e*AD + tid] + eb[e*AD + tid];
        const float w    = wsh[e];
        acc += (w > 0.f ? w : 0.f) * nv;
        __syncthreads();
    }
    hw[(long)m * AD + tid] = f2bf(acc);
    if (tid == 0) {
        float s = 0.f;
        for (int e = 0; e < EE; ++e) s += wsh[e];
        sumw[m] = s;
    }
}

// bf16 transpose: in [2048,128] -> out [128,2048], z-batched via strides.
__global__ __launch_bounds__(256) void transpose_bf(
    const u16* __restrict__ in, u16* __restrict__ out, long sIn, long sOut)
{
    __shared__ u16 tile[32][33];
    in  += (long)blockIdx.z * sIn;
    out += (long)blockIdx.z * sOut;
    const int x0 = blockIdx.x * 32, y0 = blockIdx.y * 32;
    const int tx = threadIdx.x & 31, ty = threadIdx.x >> 5;
    #pragma unroll
    for (int j = 0; j < 4; ++j)
        tile[ty + j*8][tx] = in[(long)(y0 + ty + j*8) * AD + x0 + tx];
    __syncthreads();
    #pragma unroll
    for (int j = 0; j < 4; ++j)
        out[(long)(x0 + ty + j*8) * SS + y0 + tx] = tile[tx][ty + j*8];
}

// f32 -> bf16, 4 elements/thread
__global__ __launch_bounds__(256) void cvt_bf16(
    const float* __restrict__ in, u16* __restrict__ out, long n4)
{
    const long i = (long)blockIdx.x * 256 + threadIdx.x;
    if (i < n4) {
        const float4 v = ((const float4*)in)[i];
        ushort4 o;
        o.x = f2bf(v.x); o.y = f2bf(v.y); o.z = f2bf(v.z); o.w = f2bf(v.w);
        ((ushort4*)out)[i] = o;
    }
}

extern "C" void kernel_launch(void* const* d_in, const int* in_sizes, int n_in,
                              void* d_out, int out_size, void* d_ws, size_t ws_size,
                              hipStream_t stream) {
    const float* x    = (const float*)d_in[0];
    const float* ew   = (const float*)d_in[1];
    const float* Wu   = (const float*)d_in[2];
    const float* bu   = (const float*)d_in[3];
    const float* Wg   = (const float*)d_in[4];
    const float* bg   = (const float*)d_in[5];
    const float* Wd   = (const float*)d_in[6];
    const float* bd   = (const float*)d_in[7];
    const float* Wpre = (const float*)d_in[8];
    const float* bpre = (const float*)d_in[9];
    const float* Wpost= (const float*)d_in[10];
    const float* bpost= (const float*)d_in[11];
    const float* ln_g = (const float*)d_in[12];
    const float* ln_b = (const float*)d_in[13];
    const float* Wap  = (const float*)d_in[14];
    const float* Aex  = (const float*)d_in[15];
    const float* eg   = (const float*)d_in[16];
    const float* eb   = (const float*)d_in[17];
    const float* Wp   = (const float*)d_in[18];
    const float* Wo   = (const float*)d_in[19];
    float* out = (float*)d_out;

    // ---- workspace layout (~99 MB) ----
    char* p = (char*)d_ws;
    auto take = [&](long bytes) -> char* {
        char* r = p; p += (bytes + 255) & ~255L; return r;
    };
    u16* x_slot  = (u16*)take(16777216);          // x_bf; sub-allocated after upgate
    u16* w1      = (u16*)take((long)HH*DD*2);     // Wu_bf, then Wd_bf
    u16* w2      = (u16*)take((long)HH*DD*2);     // Wg_bf, then Wap_bf
    u16* wpre    = (u16*)take((long)AD*DD*2);
    u16* aex     = (u16*)take((long)EE*AD*AD*2);
    u16* pre_bf  = (u16*)take((long)MM*AD*2);
    u16* ai_bf   = (u16*)take((long)MM*AD*2);
    char* shareA = take(33554432);                // hbuf f32 (32MB) / ao f32 (4MB) / aw bf16 (32MB)
    u16* hw_bf   = (u16*)take((long)MM*AD*2);
    float* sumw  = (float*)take((long)MM*4);
    u16* hidden  = (u16*)take((long)MM*HH*2);
    // sub-slots inside x_slot (x_bf dead after upgate):
    u16* x_bf   = x_slot;
    u16* aiT    = x_slot;                  // 4*AD*SS   = 1,048,576 u16
    u16* adaptb = aiT    + 4L*AD*SS;       // MM*AD     = 1,048,576
    u16* wpost  = adaptb + (long)MM*AD;    // AD*HH     =   262,144
    u16* ao_bf  = wpost  + (long)AD*HH;    // MM*AD     = 1,048,576
    u16* wo_bf  = ao_bf  + (long)MM*AD;    // DD*HH     = 2,097,152
    u16* wp_bf  = wo_bf  + (long)DD*HH;    // HH*AD     =   262,144
    u16* wpT    = wp_bf  + (long)HH*AD;    // AD*HH     =   262,144
    u16* wc_bf  = wpT    + (long)AD*HH;    // DD*AD     =   131,072   (total 6.16M u16 <= 8.38M)
    float* hbuf   = (float*)shareA;
    float* ao_f32 = (float*)shareA;
    u16*   aw     = (u16*)shareA;

    // ---- phase 1: converts needed before/at upgate ----
    cvt_bf16<<<dim3((MM*(long)DD/4 + 255)/256), 256, 0, stream>>>(x, x_bf, MM*(long)DD/4);
    cvt_bf16<<<dim3((HH*(long)DD/4 + 255)/256), 256, 0, stream>>>(Wu, w1, HH*(long)DD/4);
    cvt_bf16<<<dim3((HH*(long)DD/4 + 255)/256), 256, 0, stream>>>(Wg, w2, HH*(long)DD/4);
    cvt_bf16<<<dim3((AD*(long)DD/4 + 255)/256), 256, 0, stream>>>(Wpre, wpre, AD*(long)DD/4);
    cvt_bf16<<<dim3((EE*(long)AD*AD/4 + 255)/256), 256, 0, stream>>>(Aex, aex, EE*(long)AD*AD/4);

    // pre = bf16(x @ Wpre^T + bpre)
    mfma_nt<1><<<dim3(1,64,1), 256, 0, stream>>>(x_bf, wpre, pre_bf,
        MM, AD, DD, 0, 0, 0, bpre, nullptr, nullptr, 1.f);
    // adapt_in = bf16(LN(pre))
    ln_rows_bf<u16><<<dim3(MM), 128, 0, stream>>>(pre_bf, ai_bf, ln_g, ln_b);
    // h[e] = pre @ A[e]^T (f32)
    mfma_nt<0><<<dim3(1,64,EE), 256, 0, stream>>>(pre_bf, aex, hbuf,
        MM, AD, AD, 0, (long)AD*AD, (long)MM*AD, nullptr, nullptr, nullptr, 1.f);
    // hw = bf16(sum_e wmask*LN(h[e])); sumw
    expert_combine<<<dim3(MM), 128, 0, stream>>>(hbuf, ew, eg, eb, hw_bf, sumw);
    // hidden = bf16(silu(x@Wg^T+bg)*(x@Wu^T+bu))
    mfma_upgate<<<dim3(HH/64, MM/128, 1), 256, 0, stream>>>(x_bf, w1, w2, bu, bg, hidden);

    // ---- phase 2: x_bf / w1 / w2 slots are now free ----
    cvt_bf16<<<dim3((DD*(long)HH/4 + 255)/256), 256, 0, stream>>>(Wd, w1, DD*(long)HH/4);
    cvt_bf16<<<dim3((HH*(long)AD/4 + 255)/256), 256, 0, stream>>>(Wap, w2, HH*(long)AD/4);
    cvt_bf16<<<dim3((AD*(long)HH/4 + 255)/256), 256, 0, stream>>>(Wpost, wpost, AD*(long)HH/4);
    cvt_bf16<<<dim3((DD*(long)HH/4 + 255)/256), 256, 0, stream>>>(Wo, wo_bf, DD*(long)HH/4);
    cvt_bf16<<<dim3((HH*(long)AD/4 + 255)/256), 256, 0, stream>>>(Wp, wp_bf, HH*(long)AD/4);

    // WpT = Wp^T; Wc = bf16(Wo @ WpT^T) = Wo@Wp
    transpose_bf<<<dim3(4,64,1), 256, 0, stream>>>(wp_bf, wpT, 0, 0);
    mfma_nt<1><<<dim3(1,8,1), 256, 0, stream>>>(wo_bf, wpT, wc_bf,
        DD, AD, HH, 0, 0, 0, nullptr, nullptr, nullptr, 1.f);
    // out = 0.1 * hw @ Wc^T   (initializes d_out)
    mfma_nt<0><<<dim3(8,64,1), 256, 0, stream>>>(hw_bf, wc_bf, out,
        MM, DD, AD, 0, 0, 0, nullptr, nullptr, nullptr, 0.1f);
    // ao = f32(hidden @ Wpost^T + bpost); then bf16 LN
    mfma_nt<0><<<dim3(1,64,1), 256, 0, stream>>>(hidden, wpost, ao_f32,
        MM, AD, HH, 0, 0, 0, bpost, nullptr, nullptr, 1.f);
    ln_rows_bf<float><<<dim3(MM), 128, 0, stream>>>(ao_f32, ao_bf, ln_g, ln_b);
    // aiT[b] = ai[b]^T
    transpose_bf<<<dim3(4,64,4), 256, 0, stream>>>(ai_bf, aiT, (long)SS*AD, (long)AD*SS);
    // aw[b] = bf16(silu(clip(ai @ ao^T)))
    mfma_nt<2><<<dim3(16,16,4), 256, 0, stream>>>(ai_bf, ao_bf, aw,
        SS, SS, AD, (long)SS*AD, (long)SS*AD, (long)SS*SS, nullptr, nullptr, nullptr, 1.f);
    // adaptb[b] = bf16(aw @ aiT^T)
    mfma_nt<1><<<dim3(1,16,4), 256, 0, stream>>>(aw, aiT, adaptb,
        SS, AD, SS, (long)SS*SS, (long)AD*SS, (long)SS*AD, nullptr, nullptr, nullptr, 1.f);
    // hidden = bf16(hidden + 0.1 * adaptb @ Wap^T)   (in-place epilogue)
    mfma_nt<3><<<dim3(16,64,1), 256, 0, stream>>>(adaptb, w2, hidden,
        MM, HH, AD, 0, 0, 0, nullptr, nullptr, hidden, 0.1f);
    // out += sumw[row] * (hidden @ Wd^T + bd)
    mfma_nt<4><<<dim3(8,64,1), 256, 0, stream>>>(hidden, w1, out,
        MM, DD, HH, 0, 0, 0, bd, sumw, nullptr, 1.f);
}

// Round 3
// 460.372 us; speedup vs baseline: 5.2301x; 1.2295x over previous
//
#include <hip/hip_runtime.h>
#include <math.h>

// Problem constants
#define BB 4
#define SS 2048
#define DD 1024
#define HH 2048
#define AD 128
#define EE 8
#define MM (BB*SS)   // 8192

typedef unsigned short u16;
typedef short bf16x8 __attribute__((ext_vector_type(8)));
typedef float f32x4 __attribute__((ext_vector_type(4)));

__device__ __forceinline__ float silu_f(float x){ return x / (1.f + __expf(-x)); }

__device__ __forceinline__ u16 f2bf(float f){
    union { float f; unsigned u; } c; c.f = f;
    unsigned r = (c.u + 0x7FFFu + ((c.u >> 16) & 1u)) >> 16;
    return (u16)r;
}
__device__ __forceinline__ float bf2f(u16 u){
    union { unsigned u; float f; } c; c.u = ((unsigned)u) << 16;
    return c.f;
}

// async global->LDS, 16B per lane. LDS dest must be wave-uniform base + lane*16.
__device__ __forceinline__ void gld16(const u16* g, u16* l){
    __builtin_amdgcn_global_load_lds((const __attribute__((address_space(1))) void*)g,
                                     (__attribute__((address_space(3))) void*)l, 16, 0, 0);
}

// ---------------------------------------------------------------------------
// NT bf16 MFMA GEMM: C[M,N] = epi(A[M,K] @ B[N,K]^T). 128x128 tile, BK=32.
// EPI: 0 f32 store alpha*(acc+bias)
//      2 bf16 store silu(clip(acc,-5,5))
//      3 bf16 store f2bf(bf2f(Haux[idx]) + alpha*acc)   (in-place ok)
//      4 f32 C[idx] += rowscale[row]*(acc+bias[col])
// ---------------------------------------------------------------------------
template<int EPI>
__global__ __launch_bounds__(256,2) void mfma_nt(
    const u16* __restrict__ A, const u16* __restrict__ B, void* Cv,
    int M, int N, int K, long sA, long sB, long sC,
    const float* __restrict__ bias, const float* __restrict__ rowscale,
    u16* Haux, float alpha)
{
    __shared__ __align__(16) u16 As[128*32];
    __shared__ __align__(16) u16 Bs[128*32];
    const int t = threadIdx.x;
    const int lane = t & 63;
    const int wv = t >> 6;
    const int m0 = blockIdx.y * 128, n0 = blockIdx.x * 128;
    const u16* Ab = A + (long)blockIdx.z * sA;
    const u16* Bb = B + (long)blockIdx.z * sB;
    const int srow = t >> 2, scol = (t & 3) * 8;
    const u16* ga0 = Ab + (long)(m0 + srow) * K + scol;
    const u16* ga1 = ga0 + 64L * K;
    const u16* gb0 = Bb + (long)(n0 + srow) * K + scol;
    const u16* gb1 = gb0 + 64L * K;
    u16* la0 = As + t * 8;  u16* la1 = As + 2048 + t * 8;
    u16* lb0 = Bs + t * 8;  u16* lb1 = Bs + 2048 + t * 8;
    const int fr = lane & 15, q = lane >> 4;
    const int wm = (wv & 1) * 64, wn = (wv >> 1) * 64;

    f32x4 acc[4][4] = {};
    for (int k0 = 0; k0 < K; k0 += 32) {
        gld16(ga0 + k0, la0);
        gld16(ga1 + k0, la1);
        gld16(gb0 + k0, lb0);
        gld16(gb1 + k0, lb1);
        __syncthreads();
        bf16x8 af[4], bfr[4];
        #pragma unroll
        for (int i = 0; i < 4; ++i) af[i]  = *(const bf16x8*)&As[(wm + i*16 + fr)*32 + q*8];
        #pragma unroll
        for (int i = 0; i < 4; ++i) bfr[i] = *(const bf16x8*)&Bs[(wn + i*16 + fr)*32 + q*8];
        #pragma unroll
        for (int mi = 0; mi < 4; ++mi)
            #pragma unroll
            for (int ni = 0; ni < 4; ++ni)
                acc[mi][ni] = __builtin_amdgcn_mfma_f32_16x16x32_bf16(af[mi], bfr[ni], acc[mi][ni], 0, 0, 0);
        __syncthreads();
    }

    float* Cf = (float*)Cv + (long)blockIdx.z * sC;
    u16*   Cb = (u16*)Cv   + (long)blockIdx.z * sC;
    u16*   Hb = Haux ? Haux + (long)blockIdx.z * sC : (u16*)0;
    #pragma unroll
    for (int mi = 0; mi < 4; ++mi) {
        #pragma unroll
        for (int ni = 0; ni < 4; ++ni) {
            const int col = n0 + wn + ni*16 + fr;
            #pragma unroll
            for (int r = 0; r < 4; ++r) {
                const int row = m0 + wm + mi*16 + q*4 + r;
                const long idx = (long)row * N + col;
                float v = acc[mi][ni][r];
                if (EPI == 0) {
                    if (bias) v += bias[col];
                    Cf[idx] = alpha * v;
                } else if (EPI == 2) {
                    v = fminf(fmaxf(v, -5.f), 5.f);
                    Cb[idx] = f2bf(silu_f(v));
                } else if (EPI == 3) {
                    Cb[idx] = f2bf(bf2f(Hb[idx]) + alpha * v);
                } else {
                    v = (v + bias[col]) * rowscale[row];
                    Cf[idx] += v;
                }
            }
        }
    }
}

// ---------------------------------------------------------------------------
// Split-K NT GEMM, N fixed = 128. grid = (S, M/128, Z). Each block computes
// K-range [s*K/S, (s+1)*K/S) and stores f32 partial to P + s*sSplit + z*sC.
// ---------------------------------------------------------------------------
__global__ __launch_bounds__(256,2) void mfma_sk(
    const u16* __restrict__ A, const u16* __restrict__ B, float* __restrict__ P,
    int M, int K, int S, long sA, long sB, long sC, long sSplit)
{
    __shared__ __align__(16) u16 As[128*32];
    __shared__ __align__(16) u16 Bs[128*32];
    const int t = threadIdx.x;
    const int lane = t & 63;
    const int wv = t >> 6;
    const int s = blockIdx.x;
    const int m0 = blockIdx.y * 128;
    const u16* Ab = A + (long)blockIdx.z * sA;
    const u16* Bb = B + (long)blockIdx.z * sB;
    const int srow = t >> 2, scol = (t & 3) * 8;
    const int Ks = K / S, kBeg = s * Ks;
    const u16* ga0 = Ab + (long)(m0 + srow) * K + scol + kBeg;
    const u16* ga1 = ga0 + 64L * K;
    const u16* gb0 = Bb + (long)srow * K + scol + kBeg;
    const u16* gb1 = gb0 + 64L * K;
    u16* la0 = As + t * 8;  u16* la1 = As + 2048 + t * 8;
    u16* lb0 = Bs + t * 8;  u16* lb1 = Bs + 2048 + t * 8;
    const int fr = lane & 15, q = lane >> 4;
    const int wm = (wv & 1) * 64, wn = (wv >> 1) * 64;

    f32x4 acc[4][4] = {};
    for (int k0 = 0; k0 < Ks; k0 += 32) {
        gld16(ga0 + k0, la0);
        gld16(ga1 + k0, la1);
        gld16(gb0 + k0, lb0);
        gld16(gb1 + k0, lb1);
        __syncthreads();
        bf16x8 af[4], bfr[4];
        #pragma unroll
        for (int i = 0; i < 4; ++i) af[i]  = *(const bf16x8*)&As[(wm + i*16 + fr)*32 + q*8];
        #pragma unroll
        for (int i = 0; i < 4; ++i) bfr[i] = *(const bf16x8*)&Bs[(wn + i*16 + fr)*32 + q*8];
        #pragma unroll
        for (int mi = 0; mi < 4; ++mi)
            #pragma unroll
            for (int ni = 0; ni < 4; ++ni)
                acc[mi][ni] = __builtin_amdgcn_mfma_f32_16x16x32_bf16(af[mi], bfr[ni], acc[mi][ni], 0, 0, 0);
        __syncthreads();
    }

    float* Pf = P + (long)s * sSplit + (long)blockIdx.z * sC;
    #pragma unroll
    for (int mi = 0; mi < 4; ++mi)
        #pragma unroll
        for (int ni = 0; ni < 4; ++ni) {
            const int col = wn + ni*16 + fr;
            #pragma unroll
            for (int r = 0; r < 4; ++r) {
                const int row = m0 + wm + mi*16 + q*4 + r;
                Pf[(long)row * 128 + col] = acc[mi][ni][r];
            }
        }
}

// ---------------------------------------------------------------------------
// Fused up/gate: H[M,HH] = bf16( silu(X@Wg^T+bg) * (X@Wu^T+bu) )
// 128x128 tile, dual accumulator, BK=32.
// ---------------------------------------------------------------------------
__global__ __launch_bounds__(256,2) void mfma_upgate(
    const u16* __restrict__ X, const u16* __restrict__ Wu_, const u16* __restrict__ Wg_,
    const float* __restrict__ bu, const float* __restrict__ bg, u16* __restrict__ H)
{
    __shared__ __align__(16) u16 Xs[128*32];
    __shared__ __align__(16) u16 Us[128*32];
    __shared__ __align__(16) u16 Gs[128*32];
    const int t = threadIdx.x, lane = t & 63, wv = t >> 6;
    const int m0 = blockIdx.y * 128, n0 = blockIdx.x * 128;
    const int srow = t >> 2, scol = (t & 3) * 8;
    const u16* gx0 = X   + (long)(m0 + srow) * DD + scol;
    const u16* gx1 = gx0 + 64L * DD;
    const u16* gu0 = Wu_ + (long)(n0 + srow) * DD + scol;
    const u16* gu1 = gu0 + 64L * DD;
    const u16* gg0 = Wg_ + (long)(n0 + srow) * DD + scol;
    const u16* gg1 = gg0 + 64L * DD;
    const int fr = lane & 15, q = lane >> 4;
    const int wm = (wv & 1) * 64, wn = (wv >> 1) * 64;

    f32x4 accu[4][4] = {};
    f32x4 accg[4][4] = {};
    for (int k0 = 0; k0 < DD; k0 += 32) {
        gld16(gx0 + k0, Xs + t*8);
        gld16(gx1 + k0, Xs + 2048 + t*8);
        gld16(gu0 + k0, Us + t*8);
        gld16(gu1 + k0, Us + 2048 + t*8);
        gld16(gg0 + k0, Gs + t*8);
        gld16(gg1 + k0, Gs + 2048 + t*8);
        __syncthreads();
        bf16x8 xf[4], uf[4], gf[4];
        #pragma unroll
        for (int i = 0; i < 4; ++i) {
            xf[i] = *(const bf16x8*)&Xs[(wm + i*16 + fr)*32 + q*8];
            uf[i] = *(const bf16x8*)&Us[(wn + i*16 + fr)*32 + q*8];
            gf[i] = *(const bf16x8*)&Gs[(wn + i*16 + fr)*32 + q*8];
        }
        #pragma unroll
        for (int mi = 0; mi < 4; ++mi)
            #pragma unroll
            for (int ni = 0; ni < 4; ++ni) {
                accu[mi][ni] = __builtin_amdgcn_mfma_f32_16x16x32_bf16(xf[mi], uf[ni], accu[mi][ni], 0, 0, 0);
                accg[mi][ni] = __builtin_amdgcn_mfma_f32_16x16x32_bf16(xf[mi], gf[ni], accg[mi][ni], 0, 0, 0);
            }
        __syncthreads();
    }
    #pragma unroll
    for (int mi = 0; mi < 4; ++mi) {
        #pragma unroll
        for (int ni = 0; ni < 4; ++ni) {
            const int col = n0 + wn + ni*16 + fr;
            #pragma unroll
            for (int r = 0; r < 4; ++r) {
                const int row = m0 + wm + mi*16 + q*4 + r;
                const float u = accu[mi][ni][r] + bu[col];
                const float g = accg[mi][ni][r] + bg[col];
                H[(long)row * HH + col] = f2bf(silu_f(g) * u);
            }
        }
    }
}

// ---------------------------------------------------------------------------
// Split-K reduce + bias + (optional raw bf16 out) + LayerNorm(128) -> bf16.
// One block per row, 128 threads.
// ---------------------------------------------------------------------------
template<int S>
__global__ __launch_bounds__(128) void ln_reduce(
    const float* __restrict__ P, long sSplit, const float* __restrict__ bias,
    u16* __restrict__ raw, u16* __restrict__ ln_out,
    const float* __restrict__ g, const float* __restrict__ b)
{
    const int r = blockIdx.x, tid = threadIdx.x;
    float v = bias[tid];
    #pragma unroll
    for (int s = 0; s < S; ++s) v += P[(long)s * sSplit + (long)r * AD + tid];
    if (raw) raw[(long)r * AD + tid] = f2bf(v);
    __shared__ float red[AD], red2[AD];
    red[tid] = v; red2[tid] = v*v;
    __syncthreads();
    for (int s = 64; s > 0; s >>= 1) {
        if (tid < s) { red[tid] += red[tid+s]; red2[tid] += red2[tid+s]; }
        __syncthreads();
    }
    const float mean = red[0] * (1.f/AD);
    const float var  = red2[0] * (1.f/AD) - mean*mean;
    const float rs   = rsqrtf(var + 1e-5f);
    ln_out[(long)r * AD + tid] = f2bf((v - mean) * rs * g[tid] + b[tid]);
}

// Split-K reduce -> bf16 (no bias/LN), 4 elems/thread.
__global__ __launch_bounds__(256) void reduce_bf(
    const float* __restrict__ P, u16* __restrict__ out, long n4, int S, long stride4, float alpha)
{
    const long i = (long)blockIdx.x * 256 + threadIdx.x;
    if (i >= n4) return;
    float4 v = ((const float4*)P)[i];
    for (int s = 1; s < S; ++s) {
        const float4 w = ((const float4*)P)[i + s * stride4];
        v.x += w.x; v.y += w.y; v.z += w.z; v.w += w.w;
    }
    ushort4 o;
    o.x = f2bf(alpha*v.x); o.y = f2bf(alpha*v.y); o.z = f2bf(alpha*v.z); o.w = f2bf(alpha*v.w);
    ((ushort4*)out)[i] = o;
}

// hw[m,:] = bf16( sum_e max(ew,0)*LN(h[e,m,:]) );  sumw[m] = sum_e ew[m,e]
__global__ __launch_bounds__(128) void expert_combine(
    const float* __restrict__ h, const float* __restrict__ ew,
    const float* __restrict__ eg, const float* __restrict__ eb,
    u16* __restrict__ hw, float* __restrict__ sumw)
{
    const int m = blockIdx.x, tid = threadIdx.x;
    __shared__ float red[AD], red2[AD];
    __shared__ float wsh[EE];
    if (tid < EE) wsh[tid] = ew[(long)m * EE + tid];
    __syncthreads();
    float acc = 0.f;
    for (int e = 0; e < EE; ++e) {
        const float v = h[((long)e * MM + m) * AD + tid];
        red[tid] = v; red2[tid] = v*v;
        __syncthreads();
        for (int s = 64; s > 0; s >>= 1) {
            if (tid < s) { red[tid] += red[tid+s]; red2[tid] += red2[tid+s]; }
            __syncthreads();
        }
        const float mean = red[0] * (1.f/AD);
        const float var  = red2[0] * (1.f/AD) - mean*mean;
        const float rs   = rsqrtf(var + 1e-5f);
        const float nv   = (v - mean) * rs * eg[e*AD + tid] + eb[e*AD + tid];
        const float w    = wsh[e];
        acc += (w > 0.f ? w : 0.f) * nv;
        __syncthreads();
    }
    hw[(long)m * AD + tid] = f2bf(acc);
    if (tid == 0) {
        float s = 0.f;
        for (int e = 0; e < EE; ++e) s += wsh[e];
        sumw[m] = s;
    }
}

// bf16 transpose: in [R,128] -> out [128,R] with R=2048, z-batched via strides.
__global__ __launch_bounds__(256) void transpose_bf(
    const u16* __restrict__ in, u16* __restrict__ out, long sIn, long sOut)
{
    __shared__ u16 tile[32][33];
    in  += (long)blockIdx.z * sIn;
    out += (long)blockIdx.z * sOut;
    const int x0 = blockIdx.x * 32, y0 = blockIdx.y * 32;
    const int tx = threadIdx.x & 31, ty = threadIdx.x >> 5;
    #pragma unroll
    for (int j = 0; j < 4; ++j)
        tile[ty + j*8][tx] = in[(long)(y0 + ty + j*8) * AD + x0 + tx];
    __syncthreads();
    #pragma unroll
    for (int j = 0; j < 4; ++j)
        out[(long)(x0 + ty + j*8) * SS + y0 + tx] = tile[tx][ty + j*8];
}

// Packed f32->bf16 convert: 5 segments, 4 elems/thread. cum[] in float4 units.
struct Cvt5 { const float* in[5]; u16* out[5]; long cum[6]; };
__global__ __launch_bounds__(256) void cvt_pack(Cvt5 a)
{
    const long i = (long)blockIdx.x * 256 + threadIdx.x;
    if (i >= a.cum[5]) return;
    int s = 0;
    while (i >= a.cum[s+1]) ++s;
    const long j = i - a.cum[s];
    const float4 v = ((const float4*)a.in[s])[j];
    ushort4 o;
    o.x = f2bf(v.x); o.y = f2bf(v.y); o.z = f2bf(v.z); o.w = f2bf(v.w);
    ((ushort4*)a.out[s])[j] = o;
}

extern "C" void kernel_launch(void* const* d_in, const int* in_sizes, int n_in,
                              void* d_out, int out_size, void* d_ws, size_t ws_size,
                              hipStream_t stream) {
    const float* x    = (const float*)d_in[0];
    const float* ew   = (const float*)d_in[1];
    const float* Wu   = (const float*)d_in[2];
    const float* bu   = (const float*)d_in[3];
    const float* Wg   = (const float*)d_in[4];
    const float* bg   = (const float*)d_in[5];
    const float* Wd   = (const float*)d_in[6];
    const float* bd   = (const float*)d_in[7];
    const float* Wpre = (const float*)d_in[8];
    const float* bpre = (const float*)d_in[9];
    const float* Wpost= (const float*)d_in[10];
    const float* bpost= (const float*)d_in[11];
    const float* ln_g = (const float*)d_in[12];
    const float* ln_b = (const float*)d_in[13];
    const float* Wap  = (const float*)d_in[14];
    const float* Aex  = (const float*)d_in[15];
    const float* eg   = (const float*)d_in[16];
    const float* eb   = (const float*)d_in[17];
    const float* Wp   = (const float*)d_in[18];
    const float* Wo   = (const float*)d_in[19];
    float* out = (float*)d_out;

    // ---- workspace layout (~94.7 MB) ----
    char* p = (char*)d_ws;
    auto take = [&](long bytes) -> char* {
        char* r = p; p += (bytes + 255) & ~255L; return r;
    };
    u16* x_slot  = (u16*)take(16777216);          // x_bf in phase 1; sub-slots in phase 2
    u16* w1      = (u16*)take((long)HH*DD*2);     // Wu_bf, then Wd_bf
    u16* w2      = (u16*)take((long)HH*DD*2);     // Wg_bf, then Wap_bf
    u16* wpre    = (u16*)take((long)AD*DD*2);
    u16* aex     = (u16*)take((long)EE*AD*AD*2);
    u16* pre_bf  = (u16*)take((long)MM*AD*2);
    u16* ai_bf   = (u16*)take((long)MM*AD*2);
    char* shareA = take(33554432);                // pre-partials / hbuf f32 / wc-partials / wpost-partials / aw
    u16* hw_bf   = (u16*)take((long)MM*AD*2);
    float* sumw  = (float*)take((long)MM*4);
    u16* hidden  = (u16*)take((long)MM*HH*2);

    // x_slot sub-layout (phase 2; x_bf dead after upgate):
    u16* x_bf    = x_slot;
    u16* aiT     = x_slot;                          // 1,048,576 u16 (2MB)
    u16* adaptb  = aiT + 1048576;                   // 1,048,576 u16 (2MB)
    u16* pool    = adaptb + 1048576;                // 12MB pool
    u16* wpost_w = pool;                            // AD*HH   = 262,144
    u16* wo_bf   = wpost_w + 262144;                // DD*HH   = 2,097,152
    u16* wp_bf   = wo_bf + 2097152;                 // HH*AD   = 262,144
    u16* wpT     = wp_bf + 262144;                  // AD*HH   = 262,144
    u16* wc_bf   = wpT + 262144;                    // DD*AD   = 131,072
    u16* ao_bf   = wc_bf + 131072;                  // MM*AD   = 1,048,576
    float* awaiP = (float*)pool;                    // 2 x MM*AD f32 = 8MB (after pool contents dead)

    float* preP   = (float*)shareA;   // 4 x MM*AD f32 = 16MB
    float* hbuf   = (float*)shareA;   // EE x MM*AD f32 = 32MB
    float* wcP    = (float*)shareA;   // 8 x DD*AD f32 = 4MB
    float* wpostP = (float*)shareA;   // 8 x MM*AD f32 = 32MB
    u16*   aw     = (u16*)shareA;     // 4 x SS*SS bf16 = 32MB

    // ---- phase 1 ----
    {   // packed converts: x, Wu, Wg, Wpre, Aex
        Cvt5 a;
        a.in[0]=x;    a.out[0]=x_bf;  long n0=(long)MM*DD/4;
        a.in[1]=Wu;   a.out[1]=w1;    long n1=(long)HH*DD/4;
        a.in[2]=Wg;   a.out[2]=w2;    long n2=(long)HH*DD/4;
        a.in[3]=Wpre; a.out[3]=wpre;  long n3=(long)AD*DD/4;
        a.in[4]=Aex;  a.out[4]=aex;   long n4=(long)EE*AD*AD/4;
        a.cum[0]=0; a.cum[1]=n0; a.cum[2]=n0+n1; a.cum[3]=n0+n1+n2;
        a.cum[4]=n0+n1+n2+n3; a.cum[5]=n0+n1+n2+n3+n4;
        cvt_pack<<<dim3((a.cum[5]+255)/256), 256, 0, stream>>>(a);
    }
    // pre partials: x_bf @ Wpre^T, split-K S=4
    mfma_sk<<<dim3(4, MM/128, 1), 256, 0, stream>>>(
        x_bf, wpre, preP, MM, DD, 4, 0, 0, 0, (long)MM*AD);
    // reduce + bpre -> pre_bf, LN -> ai_bf
    ln_reduce<4><<<dim3(MM), 128, 0, stream>>>(preP, (long)MM*AD, bpre, pre_bf, ai_bf, ln_g, ln_b);
    // h[e] = pre @ A[e]^T (f32)
    mfma_nt<0><<<dim3(1, MM/128, EE), 256, 0, stream>>>(pre_bf, aex, hbuf,
        MM, AD, AD, 0, (long)AD*AD, (long)MM*AD, nullptr, nullptr, nullptr, 1.f);
    // hw = bf16(sum_e wmask*LN(h[e])); sumw
    expert_combine<<<dim3(MM), 128, 0, stream>>>(hbuf, ew, eg, eb, hw_bf, sumw);
    // hidden = bf16(silu(x@Wg^T+bg)*(x@Wu^T+bu)), 128x128 dual-acc
    mfma_upgate<<<dim3(HH/128, MM/128, 1), 256, 0, stream>>>(x_bf, w1, w2, bu, bg, hidden);

    // ---- phase 2 (x_bf / w1 / w2 now reusable) ----
    {   // packed converts: Wd, Wap, Wpost, Wo, Wp
        Cvt5 a;
        a.in[0]=Wd;    a.out[0]=w1;      long n0=(long)DD*HH/4;
        a.in[1]=Wap;   a.out[1]=w2;      long n1=(long)HH*AD/4;
        a.in[2]=Wpost; a.out[2]=wpost_w; long n2=(long)AD*HH/4;
        a.in[3]=Wo;    a.out[3]=wo_bf;   long n3=(long)DD*HH/4;
        a.in[4]=Wp;    a.out[4]=wp_bf;   long n4=(long)HH*AD/4;
        a.cum[0]=0; a.cum[1]=n0; a.cum[2]=n0+n1; a.cum[3]=n0+n1+n2;
        a.cum[4]=n0+n1+n2+n3; a.cum[5]=n0+n1+n2+n3+n4;
        cvt_pack<<<dim3((a.cum[5]+255)/256), 256, 0, stream>>>(a);
    }
    // WpT = Wp^T
    transpose_bf<<<dim3(4,64,1), 256, 0, stream>>>(wp_bf, wpT, 0, 0);
    // Wc = Wo @ WpT^T, split-K S=8 -> f32 partials -> bf16
    mfma_sk<<<dim3(8, DD/128, 1), 256, 0, stream>>>(
        wo_bf, wpT, wcP, DD, HH, 8, 0, 0, 0, (long)DD*AD);
    reduce_bf<<<dim3(((long)DD*AD/4+255)/256), 256, 0, stream>>>(
        wcP, wc_bf, (long)DD*AD/4, 8, (long)DD*AD/4, 1.f);
    // out = 0.1 * hw @ Wc^T  (initializes d_out)
    mfma_nt<0><<<dim3(DD/128, MM/128, 1), 256, 0, stream>>>(hw_bf, wc_bf, out,
        MM, DD, AD, 0, 0, 0, nullptr, nullptr, nullptr, 0.1f);
    // ao = LN(hidden @ Wpost^T + bpost): split-K S=8 + fused reduce/LN
    mfma_sk<<<dim3(8, MM/128, 1), 256, 0, stream>>>(
        hidden, wpost_w, wpostP, MM, HH, 8, 0, 0, 0, (long)MM*AD);
    ln_reduce<8><<<dim3(MM), 128, 0, stream>>>(wpostP, (long)MM*AD, bpost, nullptr, ao_bf, ln_g, ln_b);
    // aiT[b] = ai[b]^T
    transpose_bf<<<dim3(4,64,4), 256, 0, stream>>>(ai_bf, aiT, (long)SS*AD, (long)AD*SS);
    // aw[b] = bf16(silu(clip(ai @ ao^T)))
    mfma_nt<2><<<dim3(SS/128, SS/128, 4), 256, 0, stream>>>(ai_bf, ao_bf, aw,
        SS, SS, AD, (long)SS*AD, (long)SS*AD, (long)SS*SS, nullptr, nullptr, nullptr, 1.f);
    // adaptb[b] = aw @ aiT^T: split-K S=2 -> partials in pool -> bf16
    mfma_sk<<<dim3(2, SS/128, 4), 256, 0, stream>>>(
        aw, aiT, awaiP, SS, SS, 2, (long)SS*SS, (long)AD*SS, (long)SS*AD, (long)MM*AD);
    reduce_bf<<<dim3(((long)MM*AD/4+255)/256), 256, 0, stream>>>(
        awaiP, adaptb, (long)MM*AD/4, 2, (long)MM*AD/4, 1.f);
    // hidden = bf16(hidden + 0.1 * adaptb @ Wap^T)   (in-place epilogue)
    mfma_nt<3><<<dim3(HH/128, MM/128, 1), 256, 0, stream>>>(adaptb, w2, hidden,
        MM, HH, AD, 0, 0, 0, nullptr, nullptr, hidden, 0.1f);
    // out += sumw[row] * (hidden @ Wd^T + bd)
    mfma_nt<4><<<dim3(DD/128, MM/128, 1), 256, 0, stream>>>(hidden, w1, out,
        MM, DD, HH, 0, 0, 0, bd, sumw, nullptr, 1.f);
}